// Round 1
// baseline (3245.871 us; speedup 1.0000x reference)
//
#include <hip/hip_runtime.h>

#define NN  100000
#define FIN 165
#define HID 128
#define NE  3200000

// ws layout (float offsets)
#define OFF_DINV 0
#define OFF_H1   100352                    // N dinv, padded to 16B multiples
#define OFF_AGG  (OFF_H1 + NN * HID)
#define OFF_Z    (OFF_AGG + NN * HID)
// total = OFF_Z + 2*NN = 25,900,352 floats = ~98.8 MB

__global__ void k_deg_init(float* __restrict__ deg, int n) {
    int i = blockIdx.x * blockDim.x + threadIdx.x;
    if (i < n) deg[i] = 1.0f;               // self-loop
}

__global__ void k_deg_count(const int* __restrict__ dst, float* __restrict__ deg, int ne) {
    int stride = gridDim.x * blockDim.x;
    for (int i = blockIdx.x * blockDim.x + threadIdx.x; i < ne; i += stride)
        atomicAdd(&deg[dst[i]], 1.0f);
}

__global__ void k_dinv(float* __restrict__ deg, int n) {
    int i = blockIdx.x * blockDim.x + threadIdx.x;
    if (i < n) deg[i] = rsqrtf(deg[i]);     // deg >= 1 always (self-loop)
}

// h1[n][c] = sum_k x[n][k] * W1[k][c] ; tiles: 128 nodes x 128 ch x 16 k
__global__ __launch_bounds__(256) void k_gemm1(const float* __restrict__ x,
        const float* __restrict__ W1, float* __restrict__ h1, int n) {
    __shared__ alignas(16) float xT[16][132];   // [k][node], +4 pad keeps b128 align & breaks banks
    __shared__ alignas(16) float wS[16][128];   // [k][ch]
    const int tid = threadIdx.x;
    const int bm  = blockIdx.x * 128;
    const int tr  = tid >> 4;               // 0..15 node group
    const int tc  = tid & 15;               // 0..15 channel group
    float acc[8][8];
#pragma unroll
    for (int i = 0; i < 8; ++i)
#pragma unroll
        for (int j = 0; j < 8; ++j) acc[i][j] = 0.0f;

    for (int kt = 0; kt < 11; ++kt) {
        const int k0 = kt * 16;
        // x tile: 128 nodes x 16 k, lanes walk k fastest (64B coalesced chunks)
#pragma unroll
        for (int p = 0; p < 8; ++p) {
            int flat = p * 256 + tid;
            int kl = flat & 15;
            int nl = flat >> 4;
            int node = bm + nl;
            int k = k0 + kl;
            float v = (node < n && k < FIN) ? x[node * FIN + k] : 0.0f;
            xT[kl][nl] = v;
        }
        // W tile: 16 k x 128 ch, fully coalesced
#pragma unroll
        for (int p = 0; p < 8; ++p) {
            int flat = p * 256 + tid;
            int c  = flat & 127;
            int kl = flat >> 7;
            int k  = k0 + kl;
            wS[kl][c] = (k < FIN) ? W1[k * 128 + c] : 0.0f;
        }
        __syncthreads();
#pragma unroll
        for (int kk = 0; kk < 16; ++kk) {
            float4 a0 = *(const float4*)&xT[kk][tr * 8];
            float4 a1 = *(const float4*)&xT[kk][tr * 8 + 4];
            float4 b0 = *(const float4*)&wS[kk][tc * 8];
            float4 b1v = *(const float4*)&wS[kk][tc * 8 + 4];
            float a[8] = {a0.x, a0.y, a0.z, a0.w, a1.x, a1.y, a1.z, a1.w};
            float b[8] = {b0.x, b0.y, b0.z, b0.w, b1v.x, b1v.y, b1v.z, b1v.w};
#pragma unroll
            for (int i = 0; i < 8; ++i)
#pragma unroll
                for (int j = 0; j < 8; ++j)
                    acc[i][j] = fmaf(a[i], b[j], acc[i][j]);
        }
        __syncthreads();
    }
#pragma unroll
    for (int i = 0; i < 8; ++i) {
        int node = bm + tr * 8 + i;
        if (node < n) {
            float4 o0 = {acc[i][0], acc[i][1], acc[i][2], acc[i][3]};
            float4 o1 = {acc[i][4], acc[i][5], acc[i][6], acc[i][7]};
            *(float4*)&h1[node * 128 + tc * 8]     = o0;
            *(float4*)&h1[node * 128 + tc * 8 + 4] = o1;
        }
    }
}

// agg[n][c] = h1[n][c] * dinv[n]^2   (self-loop folded into init, no memset needed)
__global__ void k_agg_init(const float4* __restrict__ h1, const float* __restrict__ dinv,
                           float4* __restrict__ agg) {
    int total4 = NN * (HID / 4);
    int stride = gridDim.x * blockDim.x;
    for (int i = blockIdx.x * blockDim.x + threadIdx.x; i < total4; i += stride) {
        float di = dinv[i >> 5];
        float s = di * di;
        float4 v = h1[i];
        v.x *= s; v.y *= s; v.z *= s; v.w *= s;
        agg[i] = v;
    }
}

// one wave per edge: lanes cover 128 channels as float2; gather h1[src], atomic-add agg[dst]
__global__ __launch_bounds__(256) void k_scatter1(const int* __restrict__ src,
        const int* __restrict__ dst, const float* __restrict__ dinv,
        const float* __restrict__ h1, float* __restrict__ agg, int ne) {
    const int lane = threadIdx.x & 63;
    const int wid  = (blockIdx.x * blockDim.x + threadIdx.x) >> 6;
    const int nw   = (gridDim.x * blockDim.x) >> 6;
    for (int e = wid; e < ne; e += nw) {
        int s = src[e], d = dst[e];
        float norm = dinv[s] * dinv[d];
        float2 hv = *(const float2*)&h1[s * 128 + lane * 2];
        atomicAdd(&agg[d * 128 + lane * 2],     hv.x * norm);
        atomicAdd(&agg[d * 128 + lane * 2 + 1], hv.y * norm);
    }
}

// z[n] = relu(agg[n]+b1) @ W2 ; out[n] = b2 + z[n]*dinv[n]^2  (layer-2 self-loop init)
__global__ __launch_bounds__(256) void k_z(const float* __restrict__ agg,
        const float* __restrict__ b1, const float* __restrict__ W2,
        const float* __restrict__ b2, const float* __restrict__ dinv,
        float* __restrict__ z, float* __restrict__ out, int n) {
    int g = (blockIdx.x * blockDim.x + threadIdx.x) >> 4;   // node, 16 lanes per node
    int l = threadIdx.x & 15;
    if (g >= n) return;
    float p0 = 0.0f, p1 = 0.0f;
#pragma unroll
    for (int q = 0; q < 2; ++q) {
        int h0 = l * 8 + q * 4;
        float4 v4 = *(const float4*)&agg[g * 128 + h0];
        float vv[4] = {v4.x, v4.y, v4.z, v4.w};
#pragma unroll
        for (int j = 0; j < 4; ++j) {
            int h = h0 + j;
            float v = vv[j] + b1[h];
            v = v > 0.0f ? v : 0.0f;
            p0 = fmaf(v, W2[h * 2],     p0);
            p1 = fmaf(v, W2[h * 2 + 1], p1);
        }
    }
#pragma unroll
    for (int m = 8; m >= 1; m >>= 1) {
        p0 += __shfl_xor(p0, m, 64);
        p1 += __shfl_xor(p1, m, 64);
    }
    if (l == 0) {
        float di = dinv[g];
        float s = di * di;
        z[g * 2]     = p0;
        z[g * 2 + 1] = p1;
        out[g * 2]     = fmaf(p0, s, b2[0]);
        out[g * 2 + 1] = fmaf(p1, s, b2[1]);
    }
}

// one thread per edge: 2-channel scatter
__global__ void k_scatter2(const int* __restrict__ src, const int* __restrict__ dst,
        const float* __restrict__ dinv, const float* __restrict__ z,
        float* __restrict__ out, int ne) {
    int stride = gridDim.x * blockDim.x;
    for (int e = blockIdx.x * blockDim.x + threadIdx.x; e < ne; e += stride) {
        int s = src[e], d = dst[e];
        float norm = dinv[s] * dinv[d];
        float2 zv = *(const float2*)&z[s * 2];
        atomicAdd(&out[d * 2],     zv.x * norm);
        atomicAdd(&out[d * 2 + 1], zv.y * norm);
    }
}

extern "C" void kernel_launch(void* const* d_in, const int* in_sizes, int n_in,
                              void* d_out, int out_size, void* d_ws, size_t ws_size,
                              hipStream_t stream) {
    const float* x  = (const float*)d_in[0];
    const int*   ei = (const int*)d_in[1];
    const float* W1 = (const float*)d_in[2];
    const float* b1 = (const float*)d_in[3];
    const float* W2 = (const float*)d_in[4];
    const float* b2 = (const float*)d_in[5];
    float* out = (float*)d_out;

    const int n  = in_sizes[0] / FIN;   // 100000
    const int ne = in_sizes[1] / 2;     // 3200000
    const int* src = ei;
    const int* dst = ei + ne;

    float* ws   = (float*)d_ws;
    float* dinv = ws + OFF_DINV;
    float* h1   = ws + OFF_H1;
    float* agg  = ws + OFF_AGG;
    float* z    = ws + OFF_Z;

    k_deg_init<<<(n + 255) / 256, 256, 0, stream>>>(dinv, n);
    k_deg_count<<<2048, 256, 0, stream>>>(dst, dinv, ne);
    k_dinv<<<(n + 255) / 256, 256, 0, stream>>>(dinv, n);
    k_gemm1<<<(n + 127) / 128, 256, 0, stream>>>(x, W1, h1, n);
    k_agg_init<<<2048, 256, 0, stream>>>((const float4*)h1, dinv, (float4*)agg);
    k_scatter1<<<4096, 256, 0, stream>>>(src, dst, dinv, h1, agg, ne);
    k_z<<<(n * 16 + 255) / 256, 256, 0, stream>>>(agg, b1, W2, b2, dinv, z, out, n);
    k_scatter2<<<2048, 256, 0, stream>>>(src, dst, dinv, z, out, ne);
}

// Round 2
// 694.532 us; speedup vs baseline: 4.6735x; 4.6735x over previous
//
#include <hip/hip_runtime.h>

#define NN  100000
#define FIN 165
#define HID 128
#define NE  3200000
#define NB  391          // ceil(NN/256)

// ws layout (4-byte units)
#define OFF_DINV   0
#define OFF_H1     100352
#define OFF_Z      (OFF_H1 + NN * HID)            // 12,900,352
#define OFF_CNT    (OFF_Z + 2 * NN + 152)         // pad to keep things aligned
#define OFF_ROWPTR (OFF_CNT + 100352)
#define OFF_CURSOR (OFF_ROWPTR + 100352)
#define OFF_BSUM   (OFF_CURSOR + 100352)
#define OFF_BSUMX  (OFF_BSUM + 512)
#define OFF_EDATA  (OFF_BSUMX + 512)              // int2 array, even offset -> 8B aligned
// end = OFF_EDATA + 2*NE ~= 19.8M * 4B ~= 79.2 MB (fits: 98.8 MB worked in R0)

__global__ void k_zero(int* __restrict__ p, int n) {
    int i = blockIdx.x * blockDim.x + threadIdx.x;
    if (i < n) p[i] = 0;
}

__global__ void k_count(const int* __restrict__ dst, int* __restrict__ cnt, int ne) {
    int stride = gridDim.x * blockDim.x;
    for (int i = blockIdx.x * blockDim.x + threadIdx.x; i < ne; i += stride)
        atomicAdd(&cnt[dst[i]], 1);
}

__global__ __launch_bounds__(256) void k_blocksum(const int* __restrict__ cnt,
                                                  int* __restrict__ bsum, int n) {
    __shared__ int s[256];
    int tid = threadIdx.x;
    int i = blockIdx.x * 256 + tid;
    s[tid] = (i < n) ? cnt[i] : 0;
    __syncthreads();
    for (int off = 128; off >= 1; off >>= 1) {
        if (tid < off) s[tid] += s[tid + off];
        __syncthreads();
    }
    if (tid == 0) bsum[blockIdx.x] = s[0];
}

__global__ __launch_bounds__(512) void k_scanb(const int* __restrict__ bsum,
        int* __restrict__ bsumx, int nb, int* __restrict__ rowptr, int n, int ne) {
    __shared__ int s[512];
    int tid = threadIdx.x;
    int v = (tid < nb) ? bsum[tid] : 0;
    s[tid] = v;
    __syncthreads();
    for (int off = 1; off < 512; off <<= 1) {
        int t = (tid >= off) ? s[tid - off] : 0;
        __syncthreads();
        s[tid] += t;
        __syncthreads();
    }
    if (tid < nb) bsumx[tid] = s[tid] - v;   // exclusive
    if (tid == 0) rowptr[n] = ne;
}

// per-block exclusive scan of cnt + global offset; also emit cursor copy and dinv
__global__ __launch_bounds__(256) void k_rowptr(const int* __restrict__ cnt,
        const int* __restrict__ bsumx, int* __restrict__ rowptr,
        int* __restrict__ cursor, float* __restrict__ dinv, int n) {
    __shared__ int s[256];
    int tid = threadIdx.x;
    int i = blockIdx.x * 256 + tid;
    int c = (i < n) ? cnt[i] : 0;
    s[tid] = c;
    __syncthreads();
    for (int off = 1; off < 256; off <<= 1) {
        int t = (tid >= off) ? s[tid - off] : 0;
        __syncthreads();
        s[tid] += t;
        __syncthreads();
    }
    if (i < n) {
        int excl = s[tid] - c + bsumx[blockIdx.x];
        rowptr[i] = excl;
        cursor[i] = excl;
        dinv[i] = rsqrtf((float)c + 1.0f);   // +1 self-loop
    }
}

// h1 = x @ W1 ; 128x128x16 tiles, 8x8 register tile per thread
__global__ __launch_bounds__(256) void k_gemm1(const float* __restrict__ x,
        const float* __restrict__ W1, float* __restrict__ h1, int n) {
    __shared__ alignas(16) float xT[16][132];
    __shared__ alignas(16) float wS[16][128];
    const int tid = threadIdx.x;
    const int bm  = blockIdx.x * 128;
    const int tr  = tid >> 4;
    const int tc  = tid & 15;
    float acc[8][8];
#pragma unroll
    for (int i = 0; i < 8; ++i)
#pragma unroll
        for (int j = 0; j < 8; ++j) acc[i][j] = 0.0f;

    for (int kt = 0; kt < 11; ++kt) {
        const int k0 = kt * 16;
#pragma unroll
        for (int p = 0; p < 8; ++p) {
            int flat = p * 256 + tid;
            int kl = flat & 15;
            int nl = flat >> 4;
            int node = bm + nl;
            int k = k0 + kl;
            xT[kl][nl] = (node < n && k < FIN) ? x[node * FIN + k] : 0.0f;
        }
#pragma unroll
        for (int p = 0; p < 8; ++p) {
            int flat = p * 256 + tid;
            int c  = flat & 127;
            int kl = flat >> 7;
            int k  = k0 + kl;
            wS[kl][c] = (k < FIN) ? W1[k * 128 + c] : 0.0f;
        }
        __syncthreads();
#pragma unroll
        for (int kk = 0; kk < 16; ++kk) {
            float4 a0 = *(const float4*)&xT[kk][tr * 8];
            float4 a1 = *(const float4*)&xT[kk][tr * 8 + 4];
            float4 b0 = *(const float4*)&wS[kk][tc * 8];
            float4 b1v = *(const float4*)&wS[kk][tc * 8 + 4];
            float a[8] = {a0.x, a0.y, a0.z, a0.w, a1.x, a1.y, a1.z, a1.w};
            float b[8] = {b0.x, b0.y, b0.z, b0.w, b1v.x, b1v.y, b1v.z, b1v.w};
#pragma unroll
            for (int i = 0; i < 8; ++i)
#pragma unroll
                for (int j = 0; j < 8; ++j)
                    acc[i][j] = fmaf(a[i], b[j], acc[i][j]);
        }
        __syncthreads();
    }
#pragma unroll
    for (int i = 0; i < 8; ++i) {
        int node = bm + tr * 8 + i;
        if (node < n) {
            float4 o0 = {acc[i][0], acc[i][1], acc[i][2], acc[i][3]};
            float4 o1 = {acc[i][4], acc[i][5], acc[i][6], acc[i][7]};
            *(float4*)&h1[node * 128 + tc * 8]     = o0;
            *(float4*)&h1[node * 128 + tc * 8 + 4] = o1;
        }
    }
}

// counting-sort fill: edata[pos] = (src, norm) grouped by dst
__global__ void k_fill(const int* __restrict__ src, const int* __restrict__ dst,
        const float* __restrict__ dinv, int* __restrict__ cursor,
        int2* __restrict__ edata, int ne) {
    int stride = gridDim.x * blockDim.x;
    for (int e = blockIdx.x * blockDim.x + threadIdx.x; e < ne; e += stride) {
        int s = src[e], d = dst[e];
        float norm = dinv[s] * dinv[d];
        int pos = atomicAdd(&cursor[d], 1);
        edata[pos] = make_int2(s, __float_as_int(norm));
    }
}

// one wave per dst node: gather-side layer-1 aggregation, fused ReLU + @W2 -> z
__global__ __launch_bounds__(256) void k_agg_fused(const int* __restrict__ rowptr,
        const int2* __restrict__ edata, const float* __restrict__ h1,
        const float* __restrict__ dinv, const float* __restrict__ b1,
        const float* __restrict__ W2, float* __restrict__ z, int n) {
    const int wid  = (blockIdx.x * blockDim.x + threadIdx.x) >> 6;
    const int lane = threadIdx.x & 63;
    if (wid >= n) return;
    const int d = wid;
    const int beg = rowptr[d], end = rowptr[d + 1];
    const float di = dinv[d];
    float2 hd = *(const float2*)&h1[d * 128 + lane * 2];
    float a0 = hd.x * di * di;          // self-loop
    float a1 = hd.y * di * di;
    int j = beg;
    for (; j + 3 < end; j += 4) {
        int2 e0 = edata[j], e1 = edata[j + 1], e2 = edata[j + 2], e3 = edata[j + 3];
        float2 g0 = *(const float2*)&h1[e0.x * 128 + lane * 2];
        float2 g1 = *(const float2*)&h1[e1.x * 128 + lane * 2];
        float2 g2 = *(const float2*)&h1[e2.x * 128 + lane * 2];
        float2 g3 = *(const float2*)&h1[e3.x * 128 + lane * 2];
        float n0 = __int_as_float(e0.y), n1 = __int_as_float(e1.y);
        float n2 = __int_as_float(e2.y), n3 = __int_as_float(e3.y);
        a0 = fmaf(g0.x, n0, a0); a1 = fmaf(g0.y, n0, a1);
        a0 = fmaf(g1.x, n1, a0); a1 = fmaf(g1.y, n1, a1);
        a0 = fmaf(g2.x, n2, a0); a1 = fmaf(g2.y, n2, a1);
        a0 = fmaf(g3.x, n3, a0); a1 = fmaf(g3.y, n3, a1);
    }
    for (; j < end; ++j) {
        int2 e = edata[j];
        float2 g = *(const float2*)&h1[e.x * 128 + lane * 2];
        float nm = __int_as_float(e.y);
        a0 = fmaf(g.x, nm, a0); a1 = fmaf(g.y, nm, a1);
    }
    // fused epilogue: v = relu(a + b1), p = v @ W2 (wave reduction over 128 ch)
    float v0 = a0 + b1[lane * 2];     v0 = v0 > 0.0f ? v0 : 0.0f;
    float v1 = a1 + b1[lane * 2 + 1]; v1 = v1 > 0.0f ? v1 : 0.0f;
    float p0 = v0 * W2[(lane * 2) * 2]     + v1 * W2[(lane * 2 + 1) * 2];
    float p1 = v0 * W2[(lane * 2) * 2 + 1] + v1 * W2[(lane * 2 + 1) * 2 + 1];
#pragma unroll
    for (int m = 32; m >= 1; m >>= 1) {
        p0 += __shfl_xor(p0, m, 64);
        p1 += __shfl_xor(p1, m, 64);
    }
    if (lane == 0) {
        z[d * 2]     = p0;
        z[d * 2 + 1] = p1;
    }
}

// layer-2: one thread per dst node, gather-side over the same CSR (z is L2-resident)
__global__ __launch_bounds__(256) void k_out(const int* __restrict__ rowptr,
        const int2* __restrict__ edata, const float* __restrict__ z,
        const float* __restrict__ dinv, const float* __restrict__ b2,
        float* __restrict__ out, int n) {
    int d = blockIdx.x * blockDim.x + threadIdx.x;
    if (d >= n) return;
    int beg = rowptr[d], end = rowptr[d + 1];
    float di = dinv[d];
    float s2 = di * di;
    float2 zd = *(const float2*)&z[d * 2];
    float o0 = fmaf(zd.x, s2, b2[0]);    // self-loop + bias
    float o1 = fmaf(zd.y, s2, b2[1]);
    for (int j = beg; j < end; ++j) {
        int2 e = edata[j];
        float nm = __int_as_float(e.y);
        float2 zs = *(const float2*)&z[e.x * 2];
        o0 = fmaf(zs.x, nm, o0);
        o1 = fmaf(zs.y, nm, o1);
    }
    out[d * 2]     = o0;
    out[d * 2 + 1] = o1;
}

extern "C" void kernel_launch(void* const* d_in, const int* in_sizes, int n_in,
                              void* d_out, int out_size, void* d_ws, size_t ws_size,
                              hipStream_t stream) {
    const float* x  = (const float*)d_in[0];
    const int*   ei = (const int*)d_in[1];
    const float* W1 = (const float*)d_in[2];
    const float* b1 = (const float*)d_in[3];
    const float* W2 = (const float*)d_in[4];
    const float* b2 = (const float*)d_in[5];
    float* out = (float*)d_out;

    const int n  = in_sizes[0] / FIN;   // 100000
    const int ne = in_sizes[1] / 2;     // 3200000
    const int* src = ei;
    const int* dst = ei + ne;

    float* ws     = (float*)d_ws;
    float* dinv   = ws + OFF_DINV;
    float* h1     = ws + OFF_H1;
    float* z      = ws + OFF_Z;
    int*   cnt    = (int*)(ws + OFF_CNT);
    int*   rowptr = (int*)(ws + OFF_ROWPTR);
    int*   cursor = (int*)(ws + OFF_CURSOR);
    int*   bsum   = (int*)(ws + OFF_BSUM);
    int*   bsumx  = (int*)(ws + OFF_BSUMX);
    int2*  edata  = (int2*)(ws + OFF_EDATA);

    k_zero<<<NB, 256, 0, stream>>>(cnt, n);
    k_count<<<2048, 256, 0, stream>>>(dst, cnt, ne);
    k_blocksum<<<NB, 256, 0, stream>>>(cnt, bsum, n);
    k_scanb<<<1, 512, 0, stream>>>(bsum, bsumx, NB, rowptr, n, ne);
    k_rowptr<<<NB, 256, 0, stream>>>(cnt, bsumx, rowptr, cursor, dinv, n);
    k_gemm1<<<(n + 127) / 128, 256, 0, stream>>>(x, W1, h1, n);
    k_fill<<<2048, 256, 0, stream>>>(src, dst, dinv, cursor, edata, ne);
    k_agg_fused<<<(n * 64 + 255) / 256, 256, 0, stream>>>(rowptr, edata, h1, dinv, b1, W2, z, n);
    k_out<<<NB, 256, 0, stream>>>(rowptr, edata, z, dinv, b2, out, n);
}